// Round 1
// baseline (1133.863 us; speedup 1.0000x reference)
//
#include <hip/hip_runtime.h>
#include <math.h>

#define N_USERS_C 100000
#define N_ITEMS_C 50000
#define N_NODES_C 150000
#define N_EDGES_C 2000000
#define DIM_C 64
#define N_LAYERS_C 3
#define DECAY_C 1e-4f
#define BATCH_C 4096

// ---------------------------------------------------------------------------
// Kernel 1: edge scatter. One thread per (edge, dim). 2 atomicAdds per thread.
// agg layout: rows 0..99999 = agg_u (users), rows 100000..149999 = agg_i.
// ---------------------------------------------------------------------------
__global__ __launch_bounds__(256) void scatter_kernel(
    const float* __restrict__ user_emb, const float* __restrict__ item_emb,
    const float* __restrict__ edge_val, const int* __restrict__ edge_row,
    const int* __restrict__ edge_col, float* __restrict__ agg) {
  long long gid = (long long)blockIdx.x * blockDim.x + threadIdx.x;
  const long long total = (long long)N_EDGES_C * DIM_C;
  const long long stride = (long long)gridDim.x * blockDim.x;
  for (; gid < total; gid += stride) {
    int e = (int)(gid >> 6);
    int d = (int)(gid & 63);
    int r = edge_row[e];
    int c = edge_col[e];
    float v = edge_val[e];
    float vi = v * item_emb[(size_t)c * DIM_C + d];   // -> agg_u[r]
    float vu = v * user_emb[(size_t)r * DIM_C + d];   // -> agg_i[c]
    atomicAdd(&agg[(size_t)r * DIM_C + d], vi);
    atomicAdd(&agg[((size_t)N_USERS_C + c) * DIM_C + d], vu);
  }
}

// ---------------------------------------------------------------------------
// Kernel 2: per-node transform. W,b staged in LDS once per block.
// Each wave handles 2 consecutive nodes (shares W reads between them).
// Writes ego + 3 normalized layer outputs: out[1 + node*256 + col].
// ---------------------------------------------------------------------------
__global__ __launch_bounds__(256) void transform_kernel(
    const float* __restrict__ user_emb, const float* __restrict__ item_emb,
    const float* __restrict__ W, const float* __restrict__ b,
    const float* __restrict__ agg, float* __restrict__ out) {
  __shared__ float Ws[N_LAYERS_C * DIM_C * DIM_C];  // 48 KB
  __shared__ float bs[N_LAYERS_C * DIM_C];
  __shared__ float aggS[4][2][DIM_C];               // 4 waves x 2 nodes

  for (int i = threadIdx.x; i < N_LAYERS_C * DIM_C * DIM_C; i += 256)
    Ws[i] = W[i];
  for (int i = threadIdx.x; i < N_LAYERS_C * DIM_C; i += 256)
    bs[i] = b[i];
  __syncthreads();

  const int wave = threadIdx.x >> 6;
  const int lane = threadIdx.x & 63;
  const int wavesTotal = gridDim.x * 4;
  const int pairsTotal = N_NODES_C / 2;  // 75000 (N_NODES even)

  for (int p = blockIdx.x * 4 + wave; p < pairsTotal; p += wavesTotal) {
    const int n0 = 2 * p;
    const int n1 = 2 * p + 1;

    // stage agg rows for this wave (same-wave write->read, no barrier needed)
    aggS[wave][0][lane] = agg[(size_t)n0 * DIM_C + lane];
    aggS[wave][1][lane] = agg[(size_t)n1 * DIM_C + lane];

    // ego columns 0..63
    float e0 = (n0 < N_USERS_C) ? user_emb[(size_t)n0 * DIM_C + lane]
                                : item_emb[(size_t)(n0 - N_USERS_C) * DIM_C + lane];
    float e1 = (n1 < N_USERS_C) ? user_emb[(size_t)n1 * DIM_C + lane]
                                : item_emb[(size_t)(n1 - N_USERS_C) * DIM_C + lane];
    out[1 + (size_t)n0 * 256 + lane] = e0;
    out[1 + (size_t)n1 * 256 + lane] = e1;

    for (int l = 0; l < N_LAYERS_C; ++l) {
      float s0 = bs[l * DIM_C + lane];
      float s1 = s0;
      const float* Wl = &Ws[l * DIM_C * DIM_C];
      #pragma unroll
      for (int k = 0; k < DIM_C; k += 4) {
        float4 a0 = *(const float4*)&aggS[wave][0][k];  // broadcast
        float4 a1 = *(const float4*)&aggS[wave][1][k];
        float w0 = Wl[(k + 0) * DIM_C + lane];
        float w1 = Wl[(k + 1) * DIM_C + lane];
        float w2 = Wl[(k + 2) * DIM_C + lane];
        float w3 = Wl[(k + 3) * DIM_C + lane];
        s0 += a0.x * w0 + a0.y * w1 + a0.z * w2 + a0.w * w3;
        s1 += a1.x * w0 + a1.y * w1 + a1.z * w2 + a1.w * w3;
      }
      // leaky relu (slope 0.2)
      s0 = (s0 >= 0.f) ? s0 : 0.2f * s0;
      s1 = (s1 >= 0.f) ? s1 : 0.2f * s1;
      // row L2 norm across the 64 lanes
      float q0 = s0 * s0, q1 = s1 * s1;
      #pragma unroll
      for (int off = 32; off; off >>= 1) {
        q0 += __shfl_xor(q0, off);
        q1 += __shfl_xor(q1, off);
      }
      float v0 = s0 / fmaxf(sqrtf(q0), 1e-12f);
      float v1 = s1 / fmaxf(sqrtf(q1), 1e-12f);
      out[1 + (size_t)n0 * 256 + (size_t)(l + 1) * 64 + lane] = v0;
      out[1 + (size_t)n1 * 256 + (size_t)(l + 1) * 64 + lane] = v1;
    }
  }
}

// ---------------------------------------------------------------------------
// Kernel 3: BPR loss. One wave per batch element; float4 row loads.
// acc[0] += -log_sigmoid(pos-neg); acc[1] += 0.5*(|u|^2+|p|^2+|n|^2)
// ---------------------------------------------------------------------------
__global__ __launch_bounds__(256) void loss_kernel(
    const float* __restrict__ out, const int* __restrict__ bu,
    const int* __restrict__ bp, const int* __restrict__ bn,
    float* __restrict__ acc) {
  const int wave = threadIdx.x >> 6;
  const int lane = threadIdx.x & 63;
  const int j = blockIdx.x * 4 + wave;
  if (j >= BATCH_C) return;

  const float* urow = out + 1 + (size_t)bu[j] * 256;
  const float* prow = out + 1 + ((size_t)N_USERS_C + bp[j]) * 256;
  const float* nrow = out + 1 + ((size_t)N_USERS_C + bn[j]) * 256;

  float4 u  = ((const float4*)urow)[lane];
  float4 pp = ((const float4*)prow)[lane];
  float4 nn = ((const float4*)nrow)[lane];

  float x = u.x * (pp.x - nn.x) + u.y * (pp.y - nn.y) +
            u.z * (pp.z - nn.z) + u.w * (pp.w - nn.w);
  float r = u.x * u.x + u.y * u.y + u.z * u.z + u.w * u.w +
            pp.x * pp.x + pp.y * pp.y + pp.z * pp.z + pp.w * pp.w +
            nn.x * nn.x + nn.y * nn.y + nn.z * nn.z + nn.w * nn.w;

  #pragma unroll
  for (int off = 32; off; off >>= 1) {
    x += __shfl_xor(x, off);
    r += __shfl_xor(r, off);
  }
  if (lane == 0) {
    // stable log_sigmoid(x) = min(x,0) - log1p(exp(-|x|))
    float ls = fminf(x, 0.f) - log1pf(expf(-fabsf(x)));
    atomicAdd(&acc[0], -ls);
    atomicAdd(&acc[1], 0.5f * r);
  }
}

__global__ void finalize_kernel(const float* __restrict__ acc,
                                float* __restrict__ out) {
  out[0] = acc[0] / (float)BATCH_C + DECAY_C * acc[1] / (float)BATCH_C;
}

// ---------------------------------------------------------------------------
extern "C" void kernel_launch(void* const* d_in, const int* in_sizes, int n_in,
                              void* d_out, int out_size, void* d_ws, size_t ws_size,
                              hipStream_t stream) {
  const float* user_emb = (const float*)d_in[0];
  const float* item_emb = (const float*)d_in[1];
  const float* edge_val = (const float*)d_in[2];
  const float* W        = (const float*)d_in[3];
  const float* b        = (const float*)d_in[4];
  const int* edge_row   = (const int*)d_in[5];
  const int* edge_col   = (const int*)d_in[6];
  const int* bu         = (const int*)d_in[7];
  const int* bp         = (const int*)d_in[8];
  const int* bn         = (const int*)d_in[9];

  float* out = (float*)d_out;
  float* agg = (float*)d_ws;  // 150000 x 64 f32 = 38.4 MB
  const size_t aggBytes = (size_t)N_NODES_C * DIM_C * sizeof(float);
  float* acc = (float*)((char*)d_ws + aggBytes);  // 2 floats

  hipMemsetAsync(d_ws, 0, aggBytes + 2 * sizeof(float), stream);

  scatter_kernel<<<65536, 256, 0, stream>>>(user_emb, item_emb, edge_val,
                                            edge_row, edge_col, agg);
  transform_kernel<<<1024, 256, 0, stream>>>(user_emb, item_emb, W, b, agg, out);
  loss_kernel<<<BATCH_C / 4, 256, 0, stream>>>(out, bu, bp, bn, acc);
  finalize_kernel<<<1, 1, 0, stream>>>(acc, out);
}